// Round 19
// baseline (63.109 us; speedup 1.0000x reference)
//
#include <hip/hip_runtime.h>
#include <hip/hip_bf16.h>

typedef __attribute__((ext_vector_type(8))) short short8;
typedef __attribute__((ext_vector_type(4))) float f32x4;

#define NC    91
#define DM    64
#define CIN   128
#define NMOV  4206
#define NT    1024
#define NW    16

// arena offsets (bytes)
#define OFF_R2 0        // 34944: feats[96][128]swz256 / qkv[91][192] / f1 / F,T
#define OFF_R1 34944    // 22000: weight stage / P[91][104]+vt[16][96] / G fp32 (spans on)
#define OFF_PH 56944    // 2912:  ph fp32 [91][8]: LN partials / softmax psum slots
#define OFF_SE 59856    // 12288: ab16 [96][64] swz128 (rows 91..95 pad)
#define LDS_SZ 72144

// d_ws bf16 weight offsets (in shorts)
#define W_EMBED 0
#define W_IN    8192
#define W_OUT   20480
#define W_FF1   24576
#define W_FF2   32768
#define W_FT    40960
#define W_TOTAL 49152

__constant__ int HEXOFF[NC] = {
  55,66,77,88,99,110,
  45,56,67,78,89,100,111,
  35,46,57,68,79,90,101,112,
  25,36,47,58,69,80,91,102,113,
  15,26,37,48,59,70,81,92,103,114,
  5,16,27,38,49,60,71,82,93,104,115,
  6,17,28,39,50,61,72,83,94,105,
  7,18,29,40,51,62,73,84,95,
  8,19,30,41,52,63,74,85,
  9,20,31,42,53,64,75,
  10,21,32,43,54,65
};

#define SWZ(row, col, PB) ((row)*(PB) + ((((((col)*2)>>4)) ^ ((row)&7)) << 4) + (((col)*2)&15))

__device__ __forceinline__ short f2bf(float f) {
  __hip_bfloat16 h = __float2bfloat16(f);
  return __builtin_bit_cast(short, h);
}
__device__ __forceinline__ float bfs(short v) {
  return __builtin_bit_cast(float, ((unsigned)(unsigned short)v) << 16);
}

__device__ __forceinline__ short8 ldfrag128(const short* buf, int row, int k0) {
  return *(const short8*)((const char*)buf + SWZ(row, k0, 128));
}
__device__ __forceinline__ short8 ldfrag256(const short* buf, int row, int k0) {
  return *(const short8*)((const char*)buf + SWZ(row, k0, 256));
}
__device__ __forceinline__ void stb16_128(short* buf, int row, int col, float v) {
  *(short*)((char*)buf + SWZ(row, col, 128)) = f2bf(v);
}
// qkv [91][192] bf16, pitch 384B, 16B-slot row-XOR swizzle
__device__ __forceinline__ short8 ld_qkv8(const short* q, int r, int col) { // col%8==0
  return *(const short8*)((const char*)q + r*384 + ((((col*2)>>4) ^ (r&7)) << 4));
}
__device__ __forceinline__ void st_qkv(short* q, int r, int col, short v) {
  *(short*)((char*)q + r*384 + ((((col*2)>>4) ^ (r&7)) << 4) + ((col*2)&15)) = v;
}
__device__ __forceinline__ short ld_qkv1(const short* q, int r, int col) {
  return *(const short*)((const char*)q + r*384 + ((((col*2)>>4) ^ (r&7)) << 4) + ((col*2)&15));
}
// 16B copy from bf16 ws into swizzled LDS slot
__device__ __forceinline__ void cp8_swz(short* dst, int PB, const short* src, int r, int c8, int K) {
  short8 v = *(const short8*)(src + r*K + c8*8);
  *(short8*)((char*)dst + r*PB + ((c8 ^ (r&7)) << 4)) = v;
}

__global__ __launch_bounds__(256)
void prep_w(const float* __restrict__ embed_w, const float* __restrict__ in_w,
            const float* __restrict__ out_w, const float* __restrict__ ff1_w,
            const float* __restrict__ ff2_w, const float* __restrict__ from_w,
            const float* __restrict__ to_w, short* __restrict__ ws)
{
  int i = blockIdx.x*256 + threadIdx.x;
  if (i >= W_TOTAL) return;
  float v;
  if      (i < 8192)  v = embed_w[i];
  else if (i < 20480) v = in_w[i - 8192];
  else if (i < 24576) v = out_w[i - 20480];
  else if (i < 32768) v = ff1_w[i - 24576];
  else if (i < 40960) v = ff2_w[i - 32768];
  else if (i < 45056) v = from_w[i - 40960];
  else                v = to_w[i - 45056];
  ws[i] = f2bf(v);
}

__global__ __launch_bounds__(1024, 8)
void policy_fused(
    const float* __restrict__ x,
    const float* __restrict__ embed_b, const float* __restrict__ pos,
    const float* __restrict__ in_b,  const float* __restrict__ out_b,
    const float* __restrict__ ln1_g, const float* __restrict__ ln1_b,
    const float* __restrict__ ln2_g, const float* __restrict__ ln2_b,
    const float* __restrict__ ff1_b, const float* __restrict__ ff2_b,
    const float* __restrict__ from_b, const float* __restrict__ to_b,
    const float* __restrict__ move_bias,
    const int* __restrict__ move_from, const int* __restrict__ move_to,
    const short* __restrict__ ws,
    float* __restrict__ out)
{
  __shared__ __align__(16) char LDSA[LDS_SZ];   // 72144B -> 2 blocks/CU

  short* R2s = (short*)(LDSA + OFF_R2);
  short* R1s = (short*)(LDSA + OFF_R1);
  float* ph  = (float*)(LDSA + OFF_PH);   // [91][8]: LN partials / psum slots
  short* ab  = (short*)(LDSA + OFF_SE);   // [96][64] swz128
  short* Pb  = R1s;                       // per-head P [91][104] bf16 (pitch 208B)
  short* vt  = R1s + 9464;                // per-head V^T [16][96]
  float* G   = (float*)R1s;               // [91][96] fp32 (spans R1+PH+SE, all dead)
  short* Fb  = R2s;                       // [91][64] swz128
  short* Tb  = R2s + 5824;

  const int tid  = threadIdx.x;
  const int lane = tid & 63;
  const int wid  = tid >> 6;
  const int l15  = lane & 15;
  const int kfr  = (lane >> 4) * 8;
  const int mfr  = (lane >> 4) * 4;
  const int b    = blockIdx.x;
  const float* xb = x + (size_t)b * (CIN*121);
  const short8 zfrag = {0,0,0,0,0,0,0,0};

  // fp32 residual h in registers: tile0 = wid (all waves), tile1 = wid+16 (waves 0..7)
  f32x4 hreg0 = {0.f,0.f,0.f,0.f};
  f32x4 hreg1 = {0.f,0.f,0.f,0.f};
  const int mt0 = wid >> 2,        nt0 = wid & 3;
  const int mt1 = (wid + 16) >> 2, nt1 = (wid + 16) & 3;
  const int col0 = nt0*16 + l15, col1 = nt1*16 + l15;

  // ---- P0: feats gather -> R2 (swz256, rows 91-95 zeroed) ; stage embed_w -> R1 ----
  for (int e = tid; e < 16*NC; e += NT) {
    int c0 = e / NC, i = e - c0*NC;
    float v[8];
    #pragma unroll
    for (int u = 0; u < 8; ++u) v[u] = xb[(c0*8 + u)*121 + HEXOFF[i]];
    short8 s8;
    #pragma unroll
    for (int u = 0; u < 8; ++u) s8[u] = f2bf(v[u]);
    *(short8*)((char*)R2s + i*256 + ((c0 ^ (i&7)) << 4)) = s8;
  }
  if (tid < 320) ((unsigned*)R2s)[5824 + tid] = 0;
  for (int e = tid; e < 1024; e += NT) {               // embed_w [64][128] swz256
    int r = e >> 4, c8 = e & 15;
    cp8_swz(R1s, 256, ws + W_EMBED, r, c8, 128);
  }
  __syncthreads();

  // ---- P1: embed MFMA (K=128) -> hreg fp32 ; LN1 partials -> ph ----
  {
    {
      int ar = mt0*16 + l15, br = nt0*16 + l15;
      f32x4 acc = {0.f,0.f,0.f,0.f};
      #pragma unroll
      for (int kk = 0; kk < 4; ++kk) {
        short8 a = ldfrag256(R2s, ar, kk*32 + kfr);
        short8 w = ldfrag256(R1s, br, kk*32 + kfr);
        acc = __builtin_amdgcn_mfma_f32_16x16x32_bf16(a, w, acc, 0, 0, 0);
      }
      float eb = embed_b[col0];
      #pragma unroll
      for (int i2 = 0; i2 < 4; ++i2) {
        int m = mt0*16 + mfr + i2;
        hreg0[i2] = acc[i2] + eb + ((m < NC) ? pos[m*DM + col0] : 0.f);
      }
      #pragma unroll
      for (int i2 = 0; i2 < 4; ++i2) {
        float s = hreg0[i2], q = s*s;
        #pragma unroll
        for (int off = 1; off < 16; off <<= 1) {
          s += __shfl_xor(s, off, 64);
          q += __shfl_xor(q, off, 64);
        }
        int m = mt0*16 + mfr + i2;
        if (l15 == 0 && m < NC) { ph[m*8 + nt0*2] = s; ph[m*8 + nt0*2 + 1] = q; }
      }
    }
    if (wid < 8) {
      int ar = mt1*16 + l15, br = nt1*16 + l15;
      f32x4 acc = {0.f,0.f,0.f,0.f};
      #pragma unroll
      for (int kk = 0; kk < 4; ++kk) {
        short8 a = ldfrag256(R2s, ar, kk*32 + kfr);
        short8 w = ldfrag256(R1s, br, kk*32 + kfr);
        acc = __builtin_amdgcn_mfma_f32_16x16x32_bf16(a, w, acc, 0, 0, 0);
      }
      float eb = embed_b[col1];
      #pragma unroll
      for (int i2 = 0; i2 < 4; ++i2) {
        int m = mt1*16 + mfr + i2;
        hreg1[i2] = acc[i2] + eb + ((m < NC) ? pos[m*DM + col1] : 0.f);
      }
      #pragma unroll
      for (int i2 = 0; i2 < 4; ++i2) {
        float s = hreg1[i2], q = s*s;
        #pragma unroll
        for (int off = 1; off < 16; off <<= 1) {
          s += __shfl_xor(s, off, 64);
          q += __shfl_xor(q, off, 64);
        }
        int m = mt1*16 + mfr + i2;
        if (l15 == 0 && m < NC) { ph[m*8 + nt1*2] = s; ph[m*8 + nt1*2 + 1] = q; }
      }
    }
  }
  __syncthreads();

  // ---- P2: LN1-write (fp32 hreg -> ab bf16) ; stage Wqk -> R1 swz128 ----
  for (int e = tid; e < 1024; e += NT) {
    int r = e >> 3, c8 = e & 7;
    cp8_swz(R1s, 128, ws + W_IN, r, c8, 64);
  }
  {
    {
      float g1 = ln1_g[col0], b1 = ln1_b[col0];
      #pragma unroll
      for (int i2 = 0; i2 < 4; ++i2) {
        int m = mt0*16 + mfr + i2;
        if (m < NC) {
          float4 pa = *(const float4*)&ph[m*8];
          float4 pb = *(const float4*)&ph[m*8 + 4];
          float s = (pa.x + pa.z) + (pb.x + pb.z);
          float q = (pa.y + pa.w) + (pb.y + pb.w);
          float mean = s * (1.0f/64.0f);
          float var  = q * (1.0f/64.0f) - mean*mean;
          float rs   = rsqrtf(var + 1e-5f);
          stb16_128(ab, m, col0, (hreg0[i2] - mean)*rs*g1 + b1);
        }
      }
    }
    if (wid < 8) {
      float g1 = ln1_g[col1], b1 = ln1_b[col1];
      #pragma unroll
      for (int i2 = 0; i2 < 4; ++i2) {
        int m = mt1*16 + mfr + i2;
        if (m < NC) {
          float4 pa = *(const float4*)&ph[m*8];
          float4 pb = *(const float4*)&ph[m*8 + 4];
          float s = (pa.x + pa.z) + (pb.x + pb.z);
          float q = (pa.y + pa.w) + (pb.y + pb.w);
          float mean = s * (1.0f/64.0f);
          float var  = q * (1.0f/64.0f) - mean*mean;
          float rs   = rsqrtf(var + 1e-5f);
          stb16_128(ab, m, col1, (hreg1[i2] - mean)*rs*g1 + b1);
        }
      }
    }
  }
  __syncthreads();

  // ---- P3a: q,k MFMA (N=128,K=64) -> qkv cols 0..127 (q pre-scaled) ----
  {
    const float CS = 0.25f * 1.4426950408889634f;
    for (int t = wid; t < 48; t += NW) {
      int mt = t >> 3, nt = t & 7;
      int ar = mt*16 + l15, br = nt*16 + l15;
      f32x4 acc = {0.f,0.f,0.f,0.f};
      #pragma unroll
      for (int kk = 0; kk < 2; ++kk) {
        short8 a = ldfrag128(ab,  ar, kk*32 + kfr);
        short8 w = ldfrag128(R1s, br, kk*32 + kfr);
        acc = __builtin_amdgcn_mfma_f32_16x16x32_bf16(a, w, acc, 0, 0, 0);
      }
      int col = nt*16 + l15;
      float bia = in_b[col];
      float sc = (col < 64) ? CS : 1.0f;
      #pragma unroll
      for (int i2 = 0; i2 < 4; ++i2) {
        int m = mt*16 + mfr + i2;
        if (m < NC) st_qkv(R2s, m, col, f2bf((acc[i2] + bia) * sc));
      }
    }
  }
  __syncthreads();

  // ---- P3b (mini): stage Wv -> R1[0:8KB] ----
  for (int e = tid; e < 512; e += NT) {
    int r = e >> 3, c8 = e & 7;
    cp8_swz(R1s, 128, ws + W_IN + 8192, r, c8, 64);
  }
  __syncthreads();

  // ---- P3c: v MFMA (N=64) -> qkv cols 128..191 ----
  for (int t = wid; t < 24; t += NW) {
    int mt = t >> 2, nt = t & 3;
    int ar = mt*16 + l15, br = nt*16 + l15;
    f32x4 acc = {0.f,0.f,0.f,0.f};
    #pragma unroll
    for (int kk = 0; kk < 2; ++kk) {
      short8 a = ldfrag128(ab,  ar, kk*32 + kfr);
      short8 w = ldfrag128(R1s, br, kk*32 + kfr);
      acc = __builtin_amdgcn_mfma_f32_16x16x32_bf16(a, w, acc, 0, 0, 0);
    }
    int col = nt*16 + l15;
    float bia = in_b[128 + col];
    #pragma unroll
    for (int i2 = 0; i2 < 4; ++i2) {
      int m = mt*16 + mfr + i2;
      if (m < NC) st_qkv(R2s, m, 128 + col, f2bf(acc[i2] + bia));
    }
  }
  __syncthreads();

  // ---- attention: per head {vt-build + S (psum slots -> ph), PV} ----
  for (int h = 0; h < 4; ++h) {
    if (h == 0) {
      // zero Pb cols 91..95 ONCE, after Wv staging (aliased bytes) is consumed.
      // PV's K spans j=0..95: vt[j>=91]=0 but 0*NaN=NaN, so P tail must be finite.
      for (int e = tid; e < 455; e += NT) {
        int i = e / 5, c = 91 + (e - (e/5)*5);
        Pb[i*104 + c] = 0;
      }
    }
    for (int e = tid; e < 1536; e += NT) {
      int d = e / 96, j = e - d*96;
      vt[d*96 + j] = (j < NC) ? ld_qkv1(R2s, j, 128 + h*16 + d) : (short)0;
    }
    for (int t = wid; t < 36; t += NW) {
      int it = t / 6, jt = t - it*6;
      short8 a = zfrag, w = zfrag;
      if (lane < 32) {
        a = ld_qkv8(R2s, jt*16 + l15, 64 + h*16 + ((lane >> 4) << 3));
        w = ld_qkv8(R2s, it*16 + l15, h*16 + ((lane >> 4) << 3));
      }
      f32x4 acc = {0.f,0.f,0.f,0.f};
      acc = __builtin_amdgcn_mfma_f32_16x16x32_bf16(a, w, acc, 0, 0, 0);
      int i = it*16 + l15;
      float p0 = exp2f(acc[0]), p1 = exp2f(acc[1]);
      float p2 = exp2f(acc[2]), p3 = exp2f(acc[3]);
      int jb = jt*16 + mfr;
      float psum = ((jb+0) < NC ? p0 : 0.f) + ((jb+1) < NC ? p1 : 0.f)
                 + ((jb+2) < NC ? p2 : 0.f) + ((jb+3) < NC ? p3 : 0.f);
      psum += __shfl_xor(psum, 16, 64);
      psum += __shfl_xor(psum, 32, 64);
      if (i < NC) {
        if ((jb+0) < NC) Pb[i*104 + jb+0] = f2bf(p0);
        if ((jb+1) < NC) Pb[i*104 + jb+1] = f2bf(p1);
        if ((jb+2) < NC) Pb[i*104 + jb+2] = f2bf(p2);
        if ((jb+3) < NC) Pb[i*104 + jb+3] = f2bf(p3);
        if (lane < 16) ph[i*8 + jt] = psum;   // deterministic slot, no atomics
      }
    }
    __syncthreads();

    // PV: C[d][i] (A=vt rows d, B=P rows i, K=96); lsum = fixed-order 6-term sum
    for (int t = wid; t < 6; t += NW) {
      f32x4 acc = {0.f,0.f,0.f,0.f};
      #pragma unroll
      for (int kk = 0; kk < 3; ++kk) {
        int k0 = kk*32 + kfr;
        short8 a = *(const short8*)(vt + l15*96 + k0);
        short8 w = *(const short8*)((const char*)Pb + (t*16 + l15)*208 + k0*2);
        acc = __builtin_amdgcn_mfma_f32_16x16x32_bf16(a, w, acc, 0, 0, 0);
      }
      int i = t*16 + l15;
      if (i < NC) {
        float ls = ((ph[i*8+0] + ph[i*8+1]) + (ph[i*8+2] + ph[i*8+3]))
                 + (ph[i*8+4] + ph[i*8+5]);
        float li = 1.0f / ls;
        #pragma unroll
        for (int i2 = 0; i2 < 4; ++i2)
          stb16_128(ab, i, h*16 + mfr + i2, acc[i2] * li);
      }
    }
    __syncthreads();
  }

  // ---- P5c (mini): stage out_w -> R1 swz128 ----
  for (int e = tid; e < 512; e += NT) {
    int r = e >> 3, c8 = e & 7;
    cp8_swz(R1s, 128, ws + W_OUT, r, c8, 64);
  }
  __syncthreads();

  // ---- P6: out-proj MFMA: hreg += o @ out_w^T + out_b ; LN2 partials -> ph ----
  {
    {
      int ar = mt0*16 + l15, br = nt0*16 + l15;
      f32x4 acc = {0.f,0.f,0.f,0.f};
      #pragma unroll
      for (int kk = 0; kk < 2; ++kk) {
        short8 a = ldfrag128(ab,  ar, kk*32 + kfr);
        short8 w = ldfrag128(R1s, br, kk*32 + kfr);
        acc = __builtin_amdgcn_mfma_f32_16x16x32_bf16(a, w, acc, 0, 0, 0);
      }
      float ob = out_b[col0];
      #pragma unroll
      for (int i2 = 0; i2 < 4; ++i2) hreg0[i2] += acc[i2] + ob;
      #pragma unroll
      for (int i2 = 0; i2 < 4; ++i2) {
        float s = hreg0[i2], q = s*s;
        #pragma unroll
        for (int off = 1; off < 16; off <<= 1) {
          s += __shfl_xor(s, off, 64);
          q += __shfl_xor(q, off, 64);
        }
        int m = mt0*16 + mfr + i2;
        if (l15 == 0 && m < NC) { ph[m*8 + nt0*2] = s; ph[m*8 + nt0*2 + 1] = q; }
      }
    }
    if (wid < 8) {
      int ar = mt1*16 + l15, br = nt1*16 + l15;
      f32x4 acc = {0.f,0.f,0.f,0.f};
      #pragma unroll
      for (int kk = 0; kk < 2; ++kk) {
        short8 a = ldfrag128(ab,  ar, kk*32 + kfr);
        short8 w = ldfrag128(R1s, br, kk*32 + kfr);
        acc = __builtin_amdgcn_mfma_f32_16x16x32_bf16(a, w, acc, 0, 0, 0);
      }
      float ob = out_b[col1];
      #pragma unroll
      for (int i2 = 0; i2 < 4; ++i2) hreg1[i2] += acc[i2] + ob;
      #pragma unroll
      for (int i2 = 0; i2 < 4; ++i2) {
        float s = hreg1[i2], q = s*s;
        #pragma unroll
        for (int off = 1; off < 16; off <<= 1) {
          s += __shfl_xor(s, off, 64);
          q += __shfl_xor(q, off, 64);
        }
        int m = mt1*16 + mfr + i2;
        if (l15 == 0 && m < NC) { ph[m*8 + nt1*2] = s; ph[m*8 + nt1*2 + 1] = q; }
      }
    }
  }
  __syncthreads();

  // ---- P7: LN2-write (fp32 hreg -> ab) ; stage ff1 [128][64] -> R1 swz128 ----
  for (int e = tid; e < 1024; e += NT) {
    int r = e >> 3, c8 = e & 7;
    cp8_swz(R1s, 128, ws + W_FF1, r, c8, 64);
  }
  {
    {
      float g2 = ln2_g[col0], b2 = ln2_b[col0];
      #pragma unroll
      for (int i2 = 0; i2 < 4; ++i2) {
        int m = mt0*16 + mfr + i2;
        if (m < NC) {
          float4 pa = *(const float4*)&ph[m*8];
          float4 pb = *(const float4*)&ph[m*8 + 4];
          float s = (pa.x + pa.z) + (pb.x + pb.z);
          float q = (pa.y + pa.w) + (pb.y + pb.w);
          float mean = s * (1.0f/64.0f);
          float var  = q * (1.0f/64.0f) - mean*mean;
          float rs   = rsqrtf(var + 1e-5f);
          stb16_128(ab, m, col0, (hreg0[i2] - mean)*rs*g2 + b2);
        }
      }
    }
    if (wid < 8) {
      float g2 = ln2_g[col1], b2 = ln2_b[col1];
      #pragma unroll
      for (int i2 = 0; i2 < 4; ++i2) {
        int m = mt1*16 + mfr + i2;
        if (m < NC) {
          float4 pa = *(const float4*)&ph[m*8];
          float4 pb = *(const float4*)&ph[m*8 + 4];
          float s = (pa.x + pa.z) + (pb.x + pb.z);
          float q = (pa.y + pa.w) + (pb.y + pb.w);
          float mean = s * (1.0f/64.0f);
          float var  = q * (1.0f/64.0f) - mean*mean;
          float rs   = rsqrtf(var + 1e-5f);
          stb16_128(ab, m, col1, (hreg1[i2] - mean)*rs*g2 + b2);
        }
      }
    }
  }
  __syncthreads();

  // ---- P8: ff1 MFMA (N=128) -> f1 bf16 swz256 @R2 ----
  for (int t = wid; t < 48; t += NW) {
    int mt = t >> 3, nt = t & 7;
    int ar = mt*16 + l15, br = nt*16 + l15;
    f32x4 acc = {0.f,0.f,0.f,0.f};
    #pragma unroll
    for (int kk = 0; kk < 2; ++kk) {
      short8 a = ldfrag128(ab,  ar, kk*32 + kfr);
      short8 w = ldfrag128(R1s, br, kk*32 + kfr);
      acc = __builtin_amdgcn_mfma_f32_16x16x32_bf16(a, w, acc, 0, 0, 0);
    }
    int col = nt*16 + l15;
    float bia = ff1_b[col];
    #pragma unroll
    for (int i2 = 0; i2 < 4; ++i2) {
      int m = mt*16 + mfr + i2;
      if (m < NC)
        *(short*)((char*)R2s + SWZ(m, col, 256)) = f2bf(fmaxf(acc[i2] + bia, 0.f));
    }
  }
  __syncthreads();

  // ---- P8b (mini): stage ff2 [64][128] -> R1 swz256 ----
  for (int e = tid; e < 1024; e += NT) {
    int r = e >> 4, c8 = e & 15;
    cp8_swz(R1s, 256, ws + W_FF2, r, c8, 128);
  }
  __syncthreads();

  // ---- P9: ff2 MFMA (K=128): ab = bf16(hreg + f1@W^T + b) ----
  {
    {
      int ar = mt0*16 + l15, br = nt0*16 + l15;
      f32x4 acc = {0.f,0.f,0.f,0.f};
      #pragma unroll
      for (int kk = 0; kk < 4; ++kk) {
        short8 a = ldfrag256(R2s, ar, kk*32 + kfr);
        short8 w = ldfrag256(R1s, br, kk*32 + kfr);
        acc = __builtin_amdgcn_mfma_f32_16x16x32_bf16(a, w, acc, 0, 0, 0);
      }
      float bia = ff2_b[col0];
      #pragma unroll
      for (int i2 = 0; i2 < 4; ++i2) {
        int m = mt0*16 + mfr + i2;
        if (m < NC) stb16_128(ab, m, col0, hreg0[i2] + acc[i2] + bia);
      }
    }
    if (wid < 8) {
      int ar = mt1*16 + l15, br = nt1*16 + l15;
      f32x4 acc = {0.f,0.f,0.f,0.f};
      #pragma unroll
      for (int kk = 0; kk < 4; ++kk) {
        short8 a = ldfrag256(R2s, ar, kk*32 + kfr);
        short8 w = ldfrag256(R1s, br, kk*32 + kfr);
        acc = __builtin_amdgcn_mfma_f32_16x16x32_bf16(a, w, acc, 0, 0, 0);
      }
      float bia = ff2_b[col1];
      #pragma unroll
      for (int i2 = 0; i2 < 4; ++i2) {
        int m = mt1*16 + mfr + i2;
        if (m < NC) stb16_128(ab, m, col1, hreg1[i2] + acc[i2] + bia);
      }
    }
  }
  __syncthreads();

  // ---- P9b (mini): stage from/to [128][64] -> R1 swz128 ----
  for (int e = tid; e < 1024; e += NT) {
    int r = e >> 3, c8 = e & 7;
    cp8_swz(R1s, 128, ws + W_FT, r, c8, 64);
  }
  __syncthreads();

  // ---- P10: from/to MFMA -> F,T bf16 @R2 ----
  for (int t = wid; t < 48; t += NW) {
    int mt = t >> 3, nt = t & 7;
    int ar = mt*16 + l15, br = nt*16 + l15;
    f32x4 acc = {0.f,0.f,0.f,0.f};
    #pragma unroll
    for (int kk = 0; kk < 2; ++kk) {
      short8 a = ldfrag128(ab,  ar, kk*32 + kfr);
      short8 w = ldfrag128(R1s, br, kk*32 + kfr);
      acc = __builtin_amdgcn_mfma_f32_16x16x32_bf16(a, w, acc, 0, 0, 0);
    }
    int col = nt*16 + l15;
    if (nt < 4) {
      float bia = from_b[col];
      #pragma unroll
      for (int i2 = 0; i2 < 4; ++i2) {
        int m = mt*16 + mfr + i2;
        if (m < NC) stb16_128(Fb, m, col, acc[i2] + bia);
      }
    } else {
      int c2 = col - 64;
      float bia = to_b[c2];
      #pragma unroll
      for (int i2 = 0; i2 < 4; ++i2) {
        int m = mt*16 + mfr + i2;
        if (m < NC) stb16_128(Tb, m, c2, acc[i2] + bia);
      }
    }
  }
  __syncthreads();

  // ---- P11: gram MFMA: G = F @ T^T -> fp32 [91][96] over dead R1+PH+SE ----
  for (int t = wid; t < 36; t += NW) {
    int mt = t / 6, nt = t - mt*6;
    int ar = mt*16 + l15, br = nt*16 + l15;
    f32x4 acc = {0.f,0.f,0.f,0.f};
    #pragma unroll
    for (int kk = 0; kk < 2; ++kk) {
      short8 a = ldfrag128(Fb, ar, kk*32 + kfr);
      short8 w = ldfrag128(Tb, br, kk*32 + kfr);
      acc = __builtin_amdgcn_mfma_f32_16x16x32_bf16(a, w, acc, 0, 0, 0);
    }
    int col = nt*16 + l15;
    #pragma unroll
    for (int i2 = 0; i2 < 4; ++i2) {
      int m = mt*16 + mfr + i2;
      if (m < NC) G[m*96 + col] = acc[i2];
    }
  }
  __syncthreads();

  // ---- P12: logits gather ----
  {
    float* ob = out + (size_t)b * NMOV;
    for (int m = tid; m < NMOV; m += NT) {
      ob[m] = G[move_from[m]*96 + move_to[m]] + move_bias[m];
    }
  }
}

extern "C" void kernel_launch(void* const* d_in, const int* in_sizes, int n_in,
                              void* d_out, int out_size, void* d_ws, size_t ws_size,
                              hipStream_t stream) {
  const float* x        = (const float*)d_in[0];
  const float* embed_w  = (const float*)d_in[1];
  const float* embed_b  = (const float*)d_in[2];
  const float* pos      = (const float*)d_in[3];
  const float* in_w     = (const float*)d_in[4];
  const float* in_b     = (const float*)d_in[5];
  const float* out_w    = (const float*)d_in[6];
  const float* out_b    = (const float*)d_in[7];
  const float* ln1_g    = (const float*)d_in[8];
  const float* ln1_b    = (const float*)d_in[9];
  const float* ln2_g    = (const float*)d_in[10];
  const float* ln2_b    = (const float*)d_in[11];
  const float* ff1_w    = (const float*)d_in[12];
  const float* ff1_b    = (const float*)d_in[13];
  const float* ff2_w    = (const float*)d_in[14];
  const float* ff2_b    = (const float*)d_in[15];
  const float* from_w   = (const float*)d_in[16];
  const float* from_b   = (const float*)d_in[17];
  const float* to_w     = (const float*)d_in[18];
  const float* to_b     = (const float*)d_in[19];
  const float* move_bias= (const float*)d_in[20];
  const int*   move_from= (const int*)d_in[21];
  const int*   move_to  = (const int*)d_in[22];

  short* wsb = (short*)d_ws;
  prep_w<<<dim3((W_TOTAL + 255)/256), dim3(256), 0, stream>>>(
      embed_w, in_w, out_w, ff1_w, ff2_w, from_w, to_w, wsb);

  int B = in_sizes[0] / (CIN * 121);
  policy_fused<<<dim3(B), dim3(NT), 0, stream>>>(
      x, embed_b, pos, in_b, out_b,
      ln1_g, ln1_b, ln2_g, ln2_b, ff1_b, ff2_b,
      from_b, to_b, move_bias, move_from, move_to,
      (const short*)wsb, (float*)d_out);
}